// Round 11
// baseline (65.206 us; speedup 1.0000x reference)
//
#include <hip/hip_runtime.h>
#include <hip/hip_bf16.h>

// OnlineTripletLoss: B=8192, D=128, fp32 embeddings, int32 labels, scalar out.
// Symmetric upper-triangle 128x128 tiling (halves LDS/MFMA/VALU/staging work);
// 16x16x32 bf16 MFMA (VGPR-lean, round-8's 32x32+extras spilled at 128 regs);
// dual-side reduction per tile: row-side in regs (sqj-2acc space), col-side
// via shfl + per-col atomics (sqi-2acc space). 3-buffer LDS pipeline, counted
// vmcnt, raw s_barrier; row&15 source-pre-swizzle; deterministic finalize.

#define BB 8192
#define DD 128
#define MARGIN 0.2f
#define EPS 1e-12f

#define TILE 128                               // rows AND cols per block
#define NBLKT (BB / TILE)                      // 64
#define NTRI (NBLKT * (NBLKT + 1) / 2)         // 2080 upper-triangle blocks
#define STAGE_COLS 32
#define NSTAGES (TILE / STAGE_COLS)            // 4
#define STAGE_SHORTS (STAGE_COLS * DD)         // 4096 shorts = 8 KB

typedef __attribute__((ext_vector_type(8))) short short8;
typedef __attribute__((ext_vector_type(4))) float f32x4;

__device__ inline unsigned short f2bf(float f) {
    __hip_bfloat16 h = __float2bfloat16(f);
    unsigned short u;
    __builtin_memcpy(&u, &h, 2);
    return u;
}

// ---- prep: bf16 copy + packed {sq,label} meta + init reduction state -------
__global__ __launch_bounds__(256) void prep_kernel(
    const float* __restrict__ x, const int* __restrict__ lab,
    unsigned short* __restrict__ xb, float2* __restrict__ meta,
    unsigned* __restrict__ hp2, unsigned* __restrict__ mn2,
    unsigned long long* __restrict__ fsum, unsigned* __restrict__ fdone) {
    int t = blockIdx.x * blockDim.x + threadIdx.x;   // 0 .. 8192*32-1
    int row = t >> 5;                                 // 32 threads per row
    const float4 v = reinterpret_cast<const float4*>(x)[t];

    union { unsigned short u[4]; uint2 w; } p;
    p.u[0] = f2bf(v.x); p.u[1] = f2bf(v.y);
    p.u[2] = f2bf(v.z); p.u[3] = f2bf(v.w);
    reinterpret_cast<uint2*>(xb)[t] = p.w;

    float s = v.x * v.x + v.y * v.y + v.z * v.z + v.w * v.w;
    #pragma unroll
    for (int m = 16; m >= 1; m >>= 1) s += __shfl_xor(s, m, 64);  // within 32-lane row group
    if ((t & 31) == 0) meta[row] = make_float2(s, __int_as_float(lab[row]));

    if (t < BB) { hp2[t] = 0u; mn2[t] = 0x7f800000u; }  // 0, +inf
    if (t == 0) { *fsum = 0ull; *fdone = 0u; }
}

// ---- main ------------------------------------------------------------------
// 2080 blocks = upper triangle (bi<=bj) of 64x64 tile-pairs; 512 thr = 8 waves
// x 16 rows. Each 16x16 acc tile serves BOTH reductions:
//   row-side (over j): hp/mn regs in (sqj - 2 acc) space, sqi added at end
//   col-side (over i): shfl over lhi groups in (sqi - 2 acc) space, sqj added,
//                      per-col atomics (max/min idempotent -> diag dups free)
// Coverage: pairs (i,j), tile(i)<tile(j): row-side of block (t_i,t_j) covers i,
// col-side covers j; same-tile pairs: diagonal block row-side. Self-pairs fold
// into hp harmlessly (d2 ~ 0 never beats true positives; excluded from mn by eq).
__global__ __launch_bounds__(512) void triplet_main(
    const unsigned short* __restrict__ xb, const float2* __restrict__ meta,
    unsigned* __restrict__ hp2, unsigned* __restrict__ mn2) {
    const int tid  = threadIdx.x;
    const int wave = tid >> 6;
    const int lane = tid & 63;
    const int l15  = lane & 15;
    const int lhi  = lane >> 4;

    // triangle decode: blockIdx.x -> (bi, bj), bi <= bj
    int bi = 0, rem = (int)blockIdx.x;
    while (rem >= NBLKT - bi) { rem -= NBLKT - bi; ++bi; }
    const int bj = bi + rem;
    const int rbase = bi * TILE + wave * 16;
    const int cbase = bj * TILE;

    __shared__ unsigned short sb[3][STAGE_SHORTS];   // 3 x 8 KB
    __shared__ float2 smeta[TILE];                   // 1 KB

    // A fragments: 16 rows, K=128 in 4 slices (held whole kernel).
    // mfma_f32_16x16x32_bf16 A layout: row = lane&15, k = (lane>>4)*8 + i.
    short8 a[4];
    {
        const unsigned short* ar = xb + (size_t)(rbase + l15) * DD + lhi * 8;
        #pragma unroll
        for (int s = 0; s < 4; ++s)
            a[s] = *reinterpret_cast<const short8*>(ar + s * 32);
    }

    // C/D layout: col = lane&15, row_local = (lane>>4)*4 + r.
    // Row labels packed (labels < 64): byte r = label of row lhi*4+r.
    unsigned liw = 0;
    float sqi[4];
    {
        #pragma unroll
        for (int k = 0; k < 4; ++k) {
            const float2 mt = meta[rbase + lhi * 4 + k];
            sqi[k] = mt.x;
            liw |= ((unsigned)__float_as_int(mt.y) & 255u) << (8 * k);
        }
    }
    float hp[4], mn[4];
    #pragma unroll
    for (int r = 0; r < 4; ++r) { hp[r] = -__builtin_inff(); mn[r] = __builtin_inff(); }

    if (tid < TILE) smeta[tid] = meta[cbase + tid];   // col {sq,label}

    // Stage 32 cols (8 KB): 1 x 16B gload_lds per thread. LDS dest linear;
    // global SOURCE pre-swizzled: LDS(row, b) = G(row, b ^ ((row&15)<<4)).
    auto stage = [&](int g, int buf) {
        const char* src_base = (const char*)(xb + (size_t)(cbase + g * STAGE_COLS) * DD);
        const int o   = tid * 16;                       // 0..8191
        const int row = o >> 8;                         // 0..31
        const int byt = (o & 255) ^ ((row & 15) << 4);
        const char* src = src_base + row * 256 + byt;
        char* dst = (char*)&sb[buf][0] + wave * 1024;
        __builtin_amdgcn_global_load_lds(
            (const __attribute__((address_space(1))) void*)src,
            (__attribute__((address_space(3))) void*)dst, 16, 0, 0);
    };

    auto compute_group = [&](int st, int gg, const char* base) {
        const int jl = gg * 16 + l15;                   // col within stage (0..31)
        const int rowoff = jl * 256;
        const int swz = (jl & 15) << 4;
        short8 b[4];
        #pragma unroll
        for (int s = 0; s < 4; ++s)
            b[s] = *reinterpret_cast<const short8*>(
                base + rowoff + ((s * 64 + lhi * 16) ^ swz));
        f32x4 acc = {};
        #pragma unroll
        for (int s = 0; s < 4; ++s)
            acc = __builtin_amdgcn_mfma_f32_16x16x32_bf16(a[s], b[s], acc, 0, 0, 0);

        const float2 mj = smeta[st * STAGE_COLS + jl];
        const float sqj = mj.x;
        const int   lj  = __float_as_int(mj.y) & 255;
        float hpc = -__builtin_inff(), mnc = __builtin_inff();
        #pragma unroll
        for (int r = 0; r < 4; ++r) {
            const float d2p = fmaf(acc[r], -2.0f, sqj);     // row-side (sqi deferred)
            const float d2c = fmaf(acc[r], -2.0f, sqi[r]);  // col-side (sqj deferred)
            const bool eq = (int)((liw >> (8 * r)) & 255u) == lj;
            hp[r] = fmaxf(hp[r], eq ? d2p : -__builtin_inff());
            mn[r] = fminf(mn[r], eq ? __builtin_inff() : d2p);
            hpc   = fmaxf(hpc,   eq ? d2c : -__builtin_inff());
            mnc   = fminf(mnc,   eq ? __builtin_inff() : d2c);
        }
        // col-side: fold the four lhi row-groups (lanes 16 apart), then atomics
        hpc = fmaxf(hpc, __shfl_xor(hpc, 16, 64));
        hpc = fmaxf(hpc, __shfl_xor(hpc, 32, 64));
        mnc = fminf(mnc, __shfl_xor(mnc, 16, 64));
        mnc = fminf(mnc, __shfl_xor(mnc, 32, 64));
        if (lane < 16) {                                 // lhi==0 holds result
            const int j = cbase + st * STAGE_COLS + jl;
            atomicMax(&hp2[j], __float_as_uint(fmaxf(sqj + hpc, 0.0f)));
            atomicMin(&mn2[j], __float_as_uint(sqj + mnc));  // +inf if none
        }
    };

    // ---- 3-buffer pipeline: RAW barrier + counted vmcnt --------------------
    // Clean vmcnt slate first (A/meta loads complete), then keep exactly one
    // stage in flight across each raw barrier; never drain mid-loop.
    asm volatile("s_waitcnt vmcnt(0)" ::: "memory");
    stage(0, 0);
    stage(1, 1);
    #pragma unroll
    for (int st = 0; st < NSTAGES; ++st) {
        if (st < NSTAGES - 1)
            asm volatile("s_waitcnt lgkmcnt(0) vmcnt(1)" ::: "memory");
        else
            asm volatile("s_waitcnt lgkmcnt(0) vmcnt(0)" ::: "memory");
        __builtin_amdgcn_s_barrier();
        __builtin_amdgcn_sched_barrier(0);
        if (st + 2 < NSTAGES) stage(st + 2, (st + 2) % 3);
        const char* base = (const char*)&sb[st % 3][0];
        compute_group(st, 0, base);
        __builtin_amdgcn_sched_barrier(0);   // keep live sets (and VGPRs) small
        compute_group(st, 1, base);
    }

    // row-side finish: add deferred sqi; clamp hp >= 0; reduce over 16 lanes
    #pragma unroll
    for (int r = 0; r < 4; ++r) {
        hp[r] = fmaxf(sqi[r] + hp[r], 0.0f);   // -inf (none seen) -> 0
        mn[r] = sqi[r] + mn[r];                // +inf stays +inf
    }
    #pragma unroll
    for (int m = 1; m < 16; m <<= 1) {
        #pragma unroll
        for (int r = 0; r < 4; ++r) {
            hp[r] = fmaxf(hp[r], __shfl_xor(hp[r], m, 64));
            mn[r] = fminf(mn[r], __shfl_xor(mn[r], m, 64));
        }
    }
    if (l15 == 0) {   // lanes 0,16,32,48 hold the four 4-row groups
        #pragma unroll
        for (int r = 0; r < 4; ++r) {
            const int i = rbase + lhi * 4 + r;
            atomicMax(&hp2[i], __float_as_uint(hp[r]));  // >=0: uint order == float order
            atomicMin(&mn2[i], __float_as_uint(mn[r]));  // >=0 or +inf
        }
    }
}

// ---- finalize: per-row loss + deterministic fixed-point mean ---------------
// hardest_negative = min_neq d (every row has negatives: 64 labels / 8192).
__device__ inline float d_of(float d2) {
    return (d2 > EPS) ? sqrtf(d2) : 0.0f;
}

__global__ __launch_bounds__(1024) void finalize_kernel(
    const unsigned* __restrict__ hp2, const unsigned* __restrict__ mn2,
    unsigned long long* __restrict__ fsum, unsigned* __restrict__ fdone,
    float* __restrict__ out) {
    const int i = blockIdx.x * 1024 + threadIdx.x;   // 8 blocks x 1024 rows
    const float hpv = d_of(__uint_as_float(hp2[i]));
    const float mnv = d_of(__uint_as_float(mn2[i]));
    float acc = fmaxf(hpv - mnv + MARGIN, 0.0f);

    #pragma unroll
    for (int m = 1; m < 64; m <<= 1) acc += __shfl_xor(acc, m, 64);
    __shared__ float ws[16];
    const int wave = threadIdx.x >> 6;
    if ((threadIdx.x & 63) == 0) ws[wave] = acc;
    __syncthreads();
    if (threadIdx.x == 0) {
        float s = 0.0f;
        #pragma unroll
        for (int w = 0; w < 16; ++w) s += ws[w];
        // deterministic: integer atomic adds are order-independent
        atomicAdd(fsum, (unsigned long long)((double)s * 4294967296.0));
        __threadfence();
        const unsigned old = atomicAdd(fdone, 1u);
        if (old == gridDim.x - 1) {
            const unsigned long long total = atomicAdd(fsum, 0ull);
            out[0] = (float)((double)total / 4294967296.0 / (double)BB);
        }
    }
}

extern "C" void kernel_launch(void* const* d_in, const int* in_sizes, int n_in,
                              void* d_out, int out_size, void* d_ws, size_t ws_size,
                              hipStream_t stream) {
    const float* x = (const float*)d_in[0];
    const int* lab = (const int*)d_in[1];
    float* out = (float*)d_out;

    char* ws = (char*)d_ws;
    unsigned short* xb = (unsigned short*)ws;                          // 2 MB
    float2* meta = (float2*)(ws + (size_t)BB * DD * 2);                // 64 KB
    unsigned* hp2 = (unsigned*)(ws + (size_t)BB * DD * 2 + BB * 8);
    unsigned* mn2 = (unsigned*)(ws + (size_t)BB * DD * 2 + BB * 12);
    unsigned long long* fsum = (unsigned long long*)(ws + (size_t)BB * DD * 2 + BB * 16);
    unsigned* fdone = (unsigned*)(ws + (size_t)BB * DD * 2 + BB * 16 + 8);

    prep_kernel<<<(BB * DD / 4) / 256, 256, 0, stream>>>(x, lab, xb, meta, hp2, mn2, fsum, fdone);
    triplet_main<<<NTRI, 512, 0, stream>>>(xb, meta, hp2, mn2);
    finalize_kernel<<<BB / 1024, 1024, 0, stream>>>(hp2, mn2, fsum, fdone, out);
}

// Round 12
// 47.494 us; speedup vs baseline: 1.3729x; 1.3729x over previous
//
#include <hip/hip_runtime.h>
#include <hip/hip_bf16.h>

// OnlineTripletLoss: B=8192, D=128, fp32 embeddings, int32 labels, scalar out.
// BARRIER-FREE design: 4096 fully independent waves, each 32 rows (2x 16x16
// A-tiles sharing one B-fragment) x 512 cols. Wave-private LDS double-buffer
// staged via global_load_lds with constant counted vmcnt(4); col-meta in
// block-shared LDS via benign-race duplicate staging. No __syncthreads in the
// main kernel at all -- every prior barrier-synced variant stalled >55% idle
// in lockstep phases. Row&7 source-pre-swizzle; sqi-deferred epilogue;
// deterministic fixed-point finalize.

#define BB 8192
#define DD 128
#define MARGIN 0.2f
#define EPS 1e-12f

#define GCOLS 16
#define COLS_PER_WAVE 512
#define NGROUPS (COLS_PER_WAVE / GCOLS)        // 32

typedef __attribute__((ext_vector_type(8))) short short8;
typedef __attribute__((ext_vector_type(4))) float f32x4;

__device__ inline unsigned short f2bf(float f) {
    __hip_bfloat16 h = __float2bfloat16(f);
    unsigned short u;
    __builtin_memcpy(&u, &h, 2);
    return u;
}

// ---- prep: bf16 copy + packed {sq,label} meta + init reduction state -------
__global__ __launch_bounds__(256) void prep_kernel(
    const float* __restrict__ x, const int* __restrict__ lab,
    unsigned short* __restrict__ xb, float2* __restrict__ meta,
    unsigned* __restrict__ hp2, unsigned* __restrict__ mn2,
    unsigned long long* __restrict__ fsum, unsigned* __restrict__ fdone) {
    int t = blockIdx.x * blockDim.x + threadIdx.x;   // 0 .. 8192*32-1
    int row = t >> 5;                                 // 32 threads per row
    const float4 v = reinterpret_cast<const float4*>(x)[t];

    union { unsigned short u[4]; uint2 w; } p;
    p.u[0] = f2bf(v.x); p.u[1] = f2bf(v.y);
    p.u[2] = f2bf(v.z); p.u[3] = f2bf(v.w);
    reinterpret_cast<uint2*>(xb)[t] = p.w;

    float s = v.x * v.x + v.y * v.y + v.z * v.z + v.w * v.w;
    #pragma unroll
    for (int m = 16; m >= 1; m >>= 1) s += __shfl_xor(s, m, 64);  // within 32-lane row group
    if ((t & 31) == 0) meta[row] = make_float2(s, __int_as_float(lab[row]));

    if (t < BB) { hp2[t] = 0u; mn2[t] = 0x7f800000u; }  // 0, +inf
    if (t == 0) { *fsum = 0ull; *fdone = 0u; }
}

// ---- main ------------------------------------------------------------------
// 1024 blocks x 256 thr = 4096 waves, all resident (16/CU), ALL independent.
// Block's 4 waves share one 512-col chunk (shared smeta); rows differ.
// Per wave: A = 2 tiles x 16 rows in regs; per 16-col group: 4KB B staged to
// wave-private LDS dbuf (4 gload_lds), ds_read b128 (swizzled), 8 MFMA,
// fused select/max/min epilogue in (sqj - 2 dot) space.
__global__ __launch_bounds__(256) void triplet_main(
    const unsigned short* __restrict__ xb, const float2* __restrict__ meta,
    unsigned* __restrict__ hp2, unsigned* __restrict__ mn2) {
    const int tid  = threadIdx.x;
    const int wave = tid >> 6;
    const int lane = tid & 63;
    const int l15  = lane & 15;
    const int lhi  = lane >> 4;

    const int cc    = blockIdx.x & 15;               // col chunk (shared in block)
    const int rw    = (blockIdx.x >> 4) * 4 + wave;  // 0..255 row-wave
    const int rbase = rw * 32;
    const int cbase = cc * COLS_PER_WAVE;

    __shared__ unsigned short sbuf[4][2][GCOLS * DD];  // 4 waves x 2 x 4 KB (private)
    __shared__ float2 smeta[COLS_PER_WAVE];            // 4 KB, benign-race dup writes

    // A fragments: two 16-row tiles, K=128 in 4 slices (held whole kernel).
    // mfma_f32_16x16x32_bf16 A layout: row = lane&15, k = (lane>>4)*8 + i.
    short8 a0[4], a1[4];
    {
        const unsigned short* ar0 = xb + (size_t)(rbase + l15) * DD + lhi * 8;
        const unsigned short* ar1 = ar0 + 16 * DD;
        #pragma unroll
        for (int s = 0; s < 4; ++s) {
            a0[s] = *reinterpret_cast<const short8*>(ar0 + s * 32);
            a1[s] = *reinterpret_cast<const short8*>(ar1 + s * 32);
        }
    }
    // Slot labels (C/D: col = lane&15, row_local = lhi*4 + k), packed bytes.
    unsigned li0 = 0, li1 = 0;
    #pragma unroll
    for (int k = 0; k < 4; ++k) {
        li0 |= ((unsigned)__float_as_int(meta[rbase + lhi * 4 + k].y) & 255u) << (8 * k);
        li1 |= ((unsigned)__float_as_int(meta[rbase + 16 + lhi * 4 + k].y) & 255u) << (8 * k);
    }
    float hp0[4], mn0[4], hp1[4], mn1[4];
    #pragma unroll
    for (int k = 0; k < 4; ++k) {
        hp0[k] = -__builtin_inff(); mn0[k] = __builtin_inff();
        hp1[k] = -__builtin_inff(); mn1[k] = __builtin_inff();
    }

    // Stage one 16-col group (4KB) into this wave's buf[g&1].
    // LDS dest linear; global SOURCE pre-swizzled: LDS(col,b)=G(col, b^((col&7)<<4)).
    auto stage = [&](int g) {
        const char* sb_ = (const char*)(xb + (size_t)(cbase + g * GCOLS) * DD);
        char* db = (char*)&sbuf[wave][g & 1][0];
        #pragma unroll
        for (int p = 0; p < 4; ++p) {
            const int o     = p * 1024 + lane * 16;
            const int col   = o >> 8;
            const int inner = (o & 255) ^ ((col & 7) << 4);
            __builtin_amdgcn_global_load_lds(
                (const __attribute__((address_space(1))) void*)(sb_ + col * 256 + inner),
                (__attribute__((address_space(3))) void*)(db + p * 1024), 16, 0, 0);
        }
    };

    auto body = [&](int g, bool do_stage) {
        // ds_read B fragment (swizzled) + col meta; both lgkm-counted.
        const char* bb_ = (const char*)&sbuf[wave][g & 1][0];
        short8 b[4];
        #pragma unroll
        for (int s = 0; s < 4; ++s)
            b[s] = *reinterpret_cast<const short8*>(
                bb_ + l15 * 256 + ((s * 64 + lhi * 16) ^ ((l15 & 7) << 4)));
        const float2 cm = *reinterpret_cast<const float2*>(
            (const char*)smeta + ((size_t)g * 16 + l15) * 8);
        asm volatile("s_waitcnt lgkmcnt(0)" ::: "memory");
        __builtin_amdgcn_sched_barrier(0);          // rule 18: fence before MFMA
        if (do_stage) stage(g + 2);                 // buffer free: reads done
        f32x4 acc0 = {}, acc1 = {};
        #pragma unroll
        for (int s = 0; s < 4; ++s) {
            acc0 = __builtin_amdgcn_mfma_f32_16x16x32_bf16(a0[s], b[s], acc0, 0, 0, 0);
            acc1 = __builtin_amdgcn_mfma_f32_16x16x32_bf16(a1[s], b[s], acc1, 0, 0, 0);
        }
        const float sqj = cm.x;
        const int   labj = __float_as_int(cm.y) & 255;
        #pragma unroll
        for (int k = 0; k < 4; ++k) {
            const float d0 = fmaf(acc0[k], -2.0f, sqj);   // sqj - 2 dot (sqi deferred)
            const float d1 = fmaf(acc1[k], -2.0f, sqj);
            const bool e0 = (int)((li0 >> (8 * k)) & 255u) == labj;
            const bool e1 = (int)((li1 >> (8 * k)) & 255u) == labj;
            // self-pair folds into hp: d2' ~ -sqi -> ~0 after +sqi, never wins.
            hp0[k] = fmaxf(hp0[k], e0 ? d0 : -__builtin_inff());
            mn0[k] = fminf(mn0[k], e0 ? __builtin_inff() : d0);
            hp1[k] = fmaxf(hp1[k], e1 ? d1 : -__builtin_inff());
            mn1[k] = fminf(mn1[k], e1 ? __builtin_inff() : d1);
        }
    };

    // Prologue staging: smeta (4 ops, duplicate across waves - same bytes,
    // race-benign), then groups 0 and 1 (4 ops each).
    {
        const char* msrc = (const char*)(meta + cbase);
        #pragma unroll
        for (int p = 0; p < 4; ++p)
            __builtin_amdgcn_global_load_lds(
                (const __attribute__((address_space(1))) void*)(msrc + p * 1024 + lane * 16),
                (__attribute__((address_space(3))) void*)((char*)smeta + p * 1024), 16, 0, 0);
    }
    stage(0);
    stage(1);

    // Counted-vmcnt loop invariant: at top of iter g, outstanding = group g (4)
    // + group g+1 (4) [+ prologue extras at g=0, drained by the same wait];
    // vmcnt(4) -> g's staging done, g+1 stays in flight. No barriers anywhere.
    for (int g = 0; g < NGROUPS - 2; ++g) {
        asm volatile("s_waitcnt vmcnt(4)" ::: "memory");
        body(g, true);
    }
    asm volatile("s_waitcnt vmcnt(4)" ::: "memory");
    body(NGROUPS - 2, false);
    asm volatile("s_waitcnt vmcnt(0)" ::: "memory");
    body(NGROUPS - 1, false);

    // Epilogue: add deferred sqi; clamp hp >= 0 (exact: ref max(d*posmask)>=0);
    // reduce across the 16 col-lanes; one atomic pair per row.
    #pragma unroll
    for (int k = 0; k < 4; ++k) {
        const float sqi0 = meta[rbase + lhi * 4 + k].x;
        const float sqi1 = meta[rbase + 16 + lhi * 4 + k].x;
        hp0[k] = fmaxf(sqi0 + hp0[k], 0.0f);  mn0[k] = sqi0 + mn0[k];
        hp1[k] = fmaxf(sqi1 + hp1[k], 0.0f);  mn1[k] = sqi1 + mn1[k];
    }
    #pragma unroll
    for (int m = 1; m < 16; m <<= 1) {
        #pragma unroll
        for (int k = 0; k < 4; ++k) {
            hp0[k] = fmaxf(hp0[k], __shfl_xor(hp0[k], m, 64));
            mn0[k] = fminf(mn0[k], __shfl_xor(mn0[k], m, 64));
            hp1[k] = fmaxf(hp1[k], __shfl_xor(hp1[k], m, 64));
            mn1[k] = fminf(mn1[k], __shfl_xor(mn1[k], m, 64));
        }
    }
    if (l15 == 0) {   // lanes 0,16,32,48 hold the four lhi row-groups
        #pragma unroll
        for (int k = 0; k < 4; ++k) {
            const int i0 = rbase + lhi * 4 + k;
            const int i1 = i0 + 16;
            atomicMax(&hp2[i0], __float_as_uint(hp0[k]));  // >=0: uint order == float order
            atomicMin(&mn2[i0], __float_as_uint(mn0[k]));  // >=0 or +inf
            atomicMax(&hp2[i1], __float_as_uint(hp1[k]));
            atomicMin(&mn2[i1], __float_as_uint(mn1[k]));
        }
    }
}

// ---- finalize: per-row loss + deterministic fixed-point mean ---------------
// hardest_negative = min_neq d (every row has negatives: 64 labels / 8192).
__device__ inline float d_of(float d2) {
    return (d2 > EPS) ? sqrtf(d2) : 0.0f;
}

__global__ __launch_bounds__(1024) void finalize_kernel(
    const unsigned* __restrict__ hp2, const unsigned* __restrict__ mn2,
    unsigned long long* __restrict__ fsum, unsigned* __restrict__ fdone,
    float* __restrict__ out) {
    const int i = blockIdx.x * 1024 + threadIdx.x;   // 8 blocks x 1024 rows
    const float hpv = d_of(__uint_as_float(hp2[i]));
    const float mnv = d_of(__uint_as_float(mn2[i]));
    float acc = fmaxf(hpv - mnv + MARGIN, 0.0f);

    #pragma unroll
    for (int m = 1; m < 64; m <<= 1) acc += __shfl_xor(acc, m, 64);
    __shared__ float ws[16];
    const int wave = threadIdx.x >> 6;
    if ((threadIdx.x & 63) == 0) ws[wave] = acc;
    __syncthreads();
    if (threadIdx.x == 0) {
        float s = 0.0f;
        #pragma unroll
        for (int w = 0; w < 16; ++w) s += ws[w];
        // deterministic: integer atomic adds are order-independent
        atomicAdd(fsum, (unsigned long long)((double)s * 4294967296.0));
        __threadfence();
        const unsigned old = atomicAdd(fdone, 1u);
        if (old == gridDim.x - 1) {
            const unsigned long long total = atomicAdd(fsum, 0ull);
            out[0] = (float)((double)total / 4294967296.0 / (double)BB);
        }
    }
}

extern "C" void kernel_launch(void* const* d_in, const int* in_sizes, int n_in,
                              void* d_out, int out_size, void* d_ws, size_t ws_size,
                              hipStream_t stream) {
    const float* x = (const float*)d_in[0];
    const int* lab = (const int*)d_in[1];
    float* out = (float*)d_out;

    char* ws = (char*)d_ws;
    unsigned short* xb = (unsigned short*)ws;                          // 2 MB
    float2* meta = (float2*)(ws + (size_t)BB * DD * 2);                // 64 KB
    unsigned* hp2 = (unsigned*)(ws + (size_t)BB * DD * 2 + BB * 8);
    unsigned* mn2 = (unsigned*)(ws + (size_t)BB * DD * 2 + BB * 12);
    unsigned long long* fsum = (unsigned long long*)(ws + (size_t)BB * DD * 2 + BB * 16);
    unsigned* fdone = (unsigned*)(ws + (size_t)BB * DD * 2 + BB * 16 + 8);

    prep_kernel<<<(BB * DD / 4) / 256, 256, 0, stream>>>(x, lab, xb, meta, hp2, mn2, fsum, fdone);
    triplet_main<<<1024, 256, 0, stream>>>(xb, meta, hp2, mn2);
    finalize_kernel<<<BB / 1024, 1024, 0, stream>>>(hp2, mn2, fsum, fdone, out);
}